// Round 7
// baseline (505.352 us; speedup 1.0000x reference)
//
#include <hip/hip_runtime.h>
#include <hip/hip_bf16.h>
#include <stdint.h>

typedef _Float16 f16x8 __attribute__((ext_vector_type(8)));
typedef float f32x4 __attribute__((ext_vector_type(4)));

#define MFMA_F16(A, B, C) __builtin_amdgcn_mfma_f32_16x16x32_f16(A, B, C, 0, 0, 0)

constexpr int Bb = 4, Nn = 4096, Cc = 256;
constexpr int BQ = 128;          // q rows per block (8 waves x 16)
constexpr int BK = 64;           // k/v rows per tile
constexpr int NT = Nn / BK;
constexpr int HT = NT / 2;       // tiles per block in split-K mode
constexpr int KPAD = 256;        // 512B row stride + XOR swizzle (R2-proven)
constexpr int VPAD = 64;         // 128B row stride + XOR swizzle (R2-proven)
constexpr int PPAD = 64;         // unswizzled (psw XOR spills: R4/R5/R6); stride-only change
// LDS: sK 32768 + sVt 32768 + sP 16384 = 81920 B -> 2 blocks/CU (163840 = 160KiB exactly)

constexpr size_t ASZ  = (size_t)2 * Bb * Nn * Cc;            // elems per fp16 ws array
constexpr size_t WS_NEED  = ASZ * 2 * 3;                     // hi + lo + vt (bytes)
constexpr size_t OPART_ELEMS = (size_t)2 * 2 * Bb * Nn * Cc; // 2 halves x 2 dir
constexpr size_t ML_ELEMS    = (size_t)2 * 2 * Bb * Nn * 2;
constexpr size_t WS_SPLIT = WS_NEED + OPART_ELEMS * 4 + ML_ELEMS * 4;

// ---------------- prep: fp32 -> fp16 hi/lo + transposed hi ----------------
__global__ __launch_bounds__(256)
void prep_kernel(const float* __restrict__ xa, const float* __restrict__ xb,
                 _Float16* __restrict__ hi, _Float16* __restrict__ lo,
                 _Float16* __restrict__ vt)
{
    const int n0 = blockIdx.x * 64, c0 = blockIdx.y * 64, ib = blockIdx.z;
    const float* x = ((ib >> 2) == 0 ? xa : xb) + (size_t)(ib & 3) * Nn * Cc;
    const size_t base = (size_t)ib * Nn * Cc;
    __shared__ ushort tile[64][68];
    const int t = threadIdx.x;
    const int r0 = t >> 4;            // 0..15
    const int c4 = (t & 15) * 4;      // 0,4,..,60
    #pragma unroll
    for (int ii = 0; ii < 4; ++ii) {
        const int r = r0 + ii * 16;
        float4 v = *(const float4*)&x[(size_t)(n0 + r) * Cc + c0 + c4];
        float vv[4] = {v.x, v.y, v.z, v.w};
        union { _Float16 h[4]; uint2 q; } H, L;
        #pragma unroll
        for (int e = 0; e < 4; ++e) {
            _Float16 h = (_Float16)vv[e];
            H.h[e] = h;
            L.h[e] = (_Float16)(vv[e] - (float)h);
        }
        *(uint2*)&hi[base + (size_t)(n0 + r) * Cc + c0 + c4] = H.q;
        *(uint2*)&lo[base + (size_t)(n0 + r) * Cc + c0 + c4] = L.q;
        *(uint2*)&tile[r][c4] = H.q;
    }
    __syncthreads();
    const int j4 = (t & 15) * 4;
    #pragma unroll
    for (int ii = 0; ii < 4; ++ii) {
        const int cr = r0 + ii * 16;
        ushort4 o;
        o.x = tile[j4 + 0][cr]; o.y = tile[j4 + 1][cr];
        o.z = tile[j4 + 2][cr]; o.w = tile[j4 + 3][cr];
        *(ushort4*)&vt[base + (size_t)(c0 + cr) * Nn + n0 + j4] = o;
    }
}

// ---------------- main attention ----------------
template<bool PREP, bool SPLIT>
__global__ __launch_bounds__(512, 1)
void attn_kernel(const float* __restrict__ xa, const float* __restrict__ xb,
                 const float* __restrict__ gamma_p, float* __restrict__ out,
                 const _Float16* __restrict__ hi, const _Float16* __restrict__ lo,
                 const _Float16* __restrict__ vt,
                 float* __restrict__ opart, float* __restrict__ mlbuf)
{
    const int qtile = blockIdx.x, b = blockIdx.y, zz = blockIdx.z;
    const int dir  = SPLIT ? (zz >> 1) : zz;
    const int half = SPLIT ? (zz & 1) : 0;
    const float* qsrc = (dir == 0 ? xa : xb) + (size_t)b * Nn * Cc;
    const float* ksrc = (dir == 0 ? xb : xa) + (size_t)b * Nn * Cc;
    float* outp = out + (size_t)dir * Bb * Nn * Cc + (size_t)b * Nn * Cc;
    const int qib = dir * Bb + b;
    const int kib = (dir ^ 1) * Bb + b;
    const _Float16* qhiB = hi + (size_t)qib * Nn * Cc;
    const _Float16* qloB = lo + (size_t)qib * Nn * Cc;
    const _Float16* kB   = hi + (size_t)kib * Nn * Cc;
    const _Float16* vtB  = vt + (size_t)qib * Nn * Cc;   // V^T of q-source

    __shared__ _Float16 sK[BK][KPAD];       // K (fp16 hi), rows m; XOR-swizzled
    __shared__ _Float16 sVt[Cc][VPAD];      // sVt[c][m] = V[m][c]; XOR-swizzled
    __shared__ _Float16 sP[8][16][PPAD];    // per-wave P tile [qrow][m]; unswizzled

    const int t = threadIdx.x, lane = t & 63, w = t >> 6;
    const int l15 = lane & 15, g = lane >> 4;
    const int khalf = g * 8;
    const int rsw = (l15 & 7) << 3;         // read swizzle (row = *16 + l15)

    // ---- Q fragments, negated (MFMA yields logits = -E), fp16 hi/lo ----
    f16x8 qhi[8], qlo[8];
    const int qrow = qtile * BQ + w * 16 + l15;
    if constexpr (PREP) {
        #pragma unroll
        for (int j = 0; j < 8; ++j) {
            union { uint4 u; f16x8 h; } A, C2;
            A.u  = *(const uint4*)(qhiB + (size_t)qrow * Cc + j * 32 + khalf);
            C2.u = *(const uint4*)(qloB + (size_t)qrow * Cc + j * 32 + khalf);
            A.u.x ^= 0x80008000u; A.u.y ^= 0x80008000u; A.u.z ^= 0x80008000u; A.u.w ^= 0x80008000u;
            C2.u.x ^= 0x80008000u; C2.u.y ^= 0x80008000u; C2.u.z ^= 0x80008000u; C2.u.w ^= 0x80008000u;
            qhi[j] = A.h; qlo[j] = C2.h;
        }
    } else {
        const float* qb = qsrc + (size_t)qrow * Cc;
        #pragma unroll
        for (int j = 0; j < 8; ++j) {
            float4 v0 = *(const float4*)(qb + j * 32 + khalf);
            float4 v1 = *(const float4*)(qb + j * 32 + khalf + 4);
            float xv[8] = {v0.x, v0.y, v0.z, v0.w, v1.x, v1.y, v1.z, v1.w};
            #pragma unroll
            for (int e = 0; e < 8; ++e) {
                float xn = -xv[e];
                _Float16 h = (_Float16)xn;
                qhi[j][e] = h;
                qlo[j][e] = (_Float16)(xn - (float)h);
            }
        }
    }

    f32x4 O[16];
    #pragma unroll
    for (int i = 0; i < 16; ++i) O[i] = (f32x4){0.f, 0.f, 0.f, 0.f};
    float mrow[4] = {-INFINITY, -INFINITY, -INFINITY, -INFINITY};
    float lsum[4] = {0.f, 0.f, 0.f, 0.f};

    // staging maps (512 threads: 4 uint4 per thread per array)
    const int kr = t & 63, kc = (t >> 6) * 32;     // K: row, col-chunk (8 waves x 32)
    const int vr = t >> 1, vmc = (t & 1) * 32;     // Vt: row(c), m-chunk
    const int ksw = (kr & 7) << 3;                 // write swizzles
    const int vsw = (vr & 7) << 3;
    uint4 kreg[4], vreg[4];

    auto loadRegs = [&](int m0) {
        const _Float16* kg = kB + (size_t)(m0 + kr) * Cc + kc;
        #pragma unroll
        for (int q = 0; q < 4; ++q) kreg[q] = *(const uint4*)(kg + q * 8);
        const _Float16* vg = vtB + (size_t)vr * Nn + m0 + vmc;
        #pragma unroll
        for (int q = 0; q < 4; ++q) vreg[q] = *(const uint4*)(vg + q * 8);
    };
    auto writeLDS = [&]() {
        #pragma unroll
        for (int q = 0; q < 4; ++q) *(uint4*)&sK[kr][(kc + q * 8) ^ ksw] = kreg[q];
        #pragma unroll
        for (int q = 0; q < 4; ++q) *(uint4*)&sVt[vr][(vmc + q * 8) ^ vsw] = vreg[q];
    };

    auto compute = [&]() {
        // ---- S = (-Q) K^T : q split fp16 hi/lo, k single fp16 ----
        f32x4 S[4];
        #pragma unroll
        for (int s = 0; s < 4; ++s) S[s] = (f32x4){0.f, 0.f, 0.f, 0.f};
        __builtin_amdgcn_s_setprio(1);
        #pragma unroll
        for (int j = 0; j < 8; ++j) {
            const int ko = j * 32 + khalf;
            f16x8 k0 = *(const f16x8*)&sK[l15][ko ^ rsw];
            f16x8 k1 = *(const f16x8*)&sK[16 + l15][ko ^ rsw];
            f16x8 k2 = *(const f16x8*)&sK[32 + l15][ko ^ rsw];
            f16x8 k3 = *(const f16x8*)&sK[48 + l15][ko ^ rsw];
            S[0] = MFMA_F16(qhi[j], k0, S[0]);
            S[1] = MFMA_F16(qhi[j], k1, S[1]);
            S[2] = MFMA_F16(qhi[j], k2, S[2]);
            S[3] = MFMA_F16(qhi[j], k3, S[3]);
            S[0] = MFMA_F16(qlo[j], k0, S[0]);
            S[1] = MFMA_F16(qlo[j], k1, S[1]);
            S[2] = MFMA_F16(qlo[j], k2, S[2]);
            S[3] = MFMA_F16(qlo[j], k3, S[3]);
        }
        __builtin_amdgcn_s_setprio(0);

        // ---- online softmax: per-tile max reduce; sum deferred to epilogue ----
        float tmax4[4];
        bool need = false;
        #pragma unroll
        for (int r = 0; r < 4; ++r) {
            float tm = fmaxf(fmaxf(S[0][r], S[1][r]), fmaxf(S[2][r], S[3][r]));
            #pragma unroll
            for (int off = 8; off >= 1; off >>= 1)
                tm = fmaxf(tm, __shfl_xor(tm, off, 64));
            tmax4[r] = tm;
            need = need || (tm > mrow[r] + 8.f);
        }
        if (__any(need)) {      // rescale path (rare after warmup: defer-max THR=8)
            float a4[4];
            #pragma unroll
            for (int r = 0; r < 4; ++r) {
                float mn = fmaxf(mrow[r], tmax4[r]);
                a4[r] = __expf(mrow[r] - mn);
                mrow[r] = mn;
                lsum[r] *= a4[r];
            }
            #pragma unroll
            for (int i = 0; i < 16; ++i) {
                #pragma unroll
                for (int r = 0; r < 4; ++r) O[i][r] *= a4[r];
            }
        }
        const int prow = g * 4;
        #pragma unroll
        for (int r = 0; r < 4; ++r) {
            float ps = 0.f;
            #pragma unroll
            for (int s = 0; s < 4; ++s) {
                float p = __expf(S[s][r] - mrow[r]);
                ps += p;
                sP[w][prow + r][s * 16 + l15] = (_Float16)p;
            }
            lsum[r] += ps;
        }
        // order the same-wave LDS RAW at compile time and run time (rule #18)
        asm volatile("s_waitcnt lgkmcnt(0)" ::: "memory");
        __builtin_amdgcn_sched_barrier(0);

        // ---- O += P @ V ----
        f16x8 pa0 = *(const f16x8*)&sP[w][l15][khalf];
        f16x8 pa1 = *(const f16x8*)&sP[w][l15][32 + khalf];
        __builtin_amdgcn_s_setprio(1);
        #pragma unroll
        for (int i = 0; i < 16; ++i) {
            f16x8 vb0 = *(const f16x8*)&sVt[i * 16 + l15][khalf ^ rsw];
            f16x8 vb1 = *(const f16x8*)&sVt[i * 16 + l15][(32 + khalf) ^ rsw];
            O[i] = MFMA_F16(pa0, vb0, O[i]);
            O[i] = MFMA_F16(pa1, vb1, O[i]);
        }
        __builtin_amdgcn_s_setprio(0);
    };

    const int t0 = SPLIT ? half * HT : 0;
    const int tn = SPLIT ? HT : NT;

    if constexpr (PREP) {
        loadRegs(t0 * BK);
        writeLDS();
        __syncthreads();
        for (int ti = t0; ti < t0 + tn; ++ti) {
            if (ti + 1 < t0 + tn) loadRegs((ti + 1) * BK);  // in flight during compute
            compute();
            __syncthreads();                                // all reads of LDS done
            if (ti + 1 < t0 + tn) writeLDS();               // vmcnt waits inserted here
            __syncthreads();                                // LDS ready
        }
    } else {
        const int fr = t & 63, fc = (t >> 6) * 32;
        const int fsw = (fr & 7) << 3;
        for (int ti = t0; ti < t0 + tn; ++ti) {
            const int m0 = ti * BK;
            __syncthreads();
            #pragma unroll
            for (int e = 0; e < 32; e += 4) {
                float4 kv = *(const float4*)&ksrc[(size_t)(m0 + fr) * Cc + fc + e];
                sK[fr][(fc + e + 0) ^ fsw] = (_Float16)kv.x;
                sK[fr][(fc + e + 1) ^ fsw] = (_Float16)kv.y;
                sK[fr][(fc + e + 2) ^ fsw] = (_Float16)kv.z;
                sK[fr][(fc + e + 3) ^ fsw] = (_Float16)kv.w;
                float4 xv = *(const float4*)&qsrc[(size_t)(m0 + fr) * Cc + fc + e];
                sVt[fc + e + 0][fr ^ (((fc + e + 0) & 7) << 3)] = (_Float16)xv.x;
                sVt[fc + e + 1][fr ^ (((fc + e + 1) & 7) << 3)] = (_Float16)xv.y;
                sVt[fc + e + 2][fr ^ (((fc + e + 2) & 7) << 3)] = (_Float16)xv.z;
                sVt[fc + e + 3][fr ^ (((fc + e + 3) & 7) << 3)] = (_Float16)xv.w;
            }
            __syncthreads();
            compute();
        }
    }

    // ---- epilogue ----
    if constexpr (SPLIT) {
        // write partial state: unnormalized O (fp32) + per-row (m, l)
        const size_t hb = (size_t)(half * 2 + dir) * Bb + b;
        float* op  = opart + hb * Nn * Cc;
        float* mlp = mlbuf + hb * Nn * 2;
        #pragma unroll
        for (int r = 0; r < 4; ++r) {
            float lv = lsum[r];
            #pragma unroll
            for (int off = 8; off >= 1; off >>= 1)
                lv += __shfl_xor(lv, off, 64);
            const int row = qtile * BQ + w * 16 + g * 4 + r;
            const size_t ro = (size_t)row * Cc + l15;
            #pragma unroll
            for (int i = 0; i < 16; ++i)
                op[ro + i * 16] = O[i][r];
            if (l15 == 0) {
                mlp[(size_t)row * 2 + 0] = mrow[r];
                mlp[(size_t)row * 2 + 1] = lv;
            }
        }
    } else {
        const float gma = gamma_p[0];
        #pragma unroll
        for (int r = 0; r < 4; ++r) {
            float lv = lsum[r];
            #pragma unroll
            for (int off = 8; off >= 1; off >>= 1)
                lv += __shfl_xor(lv, off, 64);
            const float inv = 1.f / lv;
            const int row = qtile * BQ + w * 16 + g * 4 + r;
            const size_t ro = (size_t)row * Cc + l15;
            #pragma unroll
            for (int i = 0; i < 16; ++i) {
                float o = O[i][r] * inv;
                outp[ro + i * 16] = gma * o + qsrc[ro + i * 16];
            }
        }
    }
}

// ---------------- merge: combine the two KV-halves ----------------
__global__ __launch_bounds__(256)
void merge_kernel(const float* __restrict__ xa, const float* __restrict__ xb,
                  const float* __restrict__ gamma_p, float* __restrict__ out,
                  const float* __restrict__ opart, const float* __restrict__ mlbuf)
{
    const int t = threadIdx.x;
    const int rin = t >> 3;                  // 0..31 (row within block)
    const int ci = (t & 7) * 8;              // float4 base index (8 per thread)
    const int gr = blockIdx.x * 32 + rin;    // global row over 2*Bb*Nn
    const int dir = gr / (Bb * Nn);
    const int rem = gr - dir * (Bb * Nn);
    const int b = rem / Nn, row = rem % Nn;
    const size_t i0 = ((size_t)(0 * 2 + dir) * Bb + b) * Nn + row;
    const size_t i1 = ((size_t)(1 * 2 + dir) * Bb + b) * Nn + row;
    const float m0 = mlbuf[i0 * 2], l0v = mlbuf[i0 * 2 + 1];
    const float m1 = mlbuf[i1 * 2], l1v = mlbuf[i1 * 2 + 1];
    const float M = fmaxf(m0, m1);
    const float w0 = __expf(m0 - M), w1 = __expf(m1 - M);
    const float inv = 1.f / (l0v * w0 + l1v * w1);
    const float gma = gamma_p[0];
    const float* x = (dir == 0 ? xa : xb) + ((size_t)b * Nn + row) * Cc;
    float* o = out + ((size_t)dir * Bb + b) * (size_t)Nn * Cc + (size_t)row * Cc;
    const float* p0 = opart + i0 * Cc;
    const float* p1 = opart + i1 * Cc;
    #pragma unroll
    for (int k = 0; k < 8; ++k) {
        const int c = (ci + k) * 4;
        float4 a0 = *(const float4*)&p0[c];
        float4 a1 = *(const float4*)&p1[c];
        float4 xv = *(const float4*)&x[c];
        float4 r4;
        r4.x = gma * (a0.x * w0 + a1.x * w1) * inv + xv.x;
        r4.y = gma * (a0.y * w0 + a1.y * w1) * inv + xv.y;
        r4.z = gma * (a0.z * w0 + a1.z * w1) * inv + xv.z;
        r4.w = gma * (a0.w * w0 + a1.w * w1) * inv + xv.w;
        *(float4*)&o[c] = r4;
    }
}

extern "C" void kernel_launch(void* const* d_in, const int* in_sizes, int n_in,
                              void* d_out, int out_size, void* d_ws, size_t ws_size,
                              hipStream_t stream) {
    (void)in_sizes; (void)n_in; (void)out_size;
    const float* xa = (const float*)d_in[0];
    const float* xb = (const float*)d_in[1];
    const float* gm = (const float*)d_in[2];
    float* out = (float*)d_out;

    if (ws_size >= WS_SPLIT) {
        _Float16* hi = (_Float16*)d_ws;
        _Float16* lo = hi + ASZ;
        _Float16* vt = lo + ASZ;
        float* opart = (float*)((char*)d_ws + WS_NEED);
        float* ml    = opart + OPART_ELEMS;
        prep_kernel<<<dim3(Nn / 64, Cc / 64, 2 * Bb), 256, 0, stream>>>(xa, xb, hi, lo, vt);
        attn_kernel<true, true><<<dim3(Nn / BQ, Bb, 4), 512, 0, stream>>>(
            xa, xb, gm, out, hi, lo, vt, opart, ml);
        merge_kernel<<<dim3(2 * Bb * Nn / 32), 256, 0, stream>>>(xa, xb, gm, out, opart, ml);
    } else if (ws_size >= WS_NEED) {
        _Float16* hi = (_Float16*)d_ws;
        _Float16* lo = hi + ASZ;
        _Float16* vt = lo + ASZ;
        prep_kernel<<<dim3(Nn / 64, Cc / 64, 2 * Bb), 256, 0, stream>>>(xa, xb, hi, lo, vt);
        attn_kernel<true, false><<<dim3(Nn / BQ, Bb, 2), 512, 0, stream>>>(
            xa, xb, gm, out, hi, lo, vt, nullptr, nullptr);
    } else {
        attn_kernel<false, false><<<dim3(Nn / BQ, Bb, 2), 512, 0, stream>>>(
            xa, xb, gm, out, nullptr, nullptr, nullptr, nullptr, nullptr);
    }
}

// Round 8
// 243.194 us; speedup vs baseline: 2.0780x; 2.0780x over previous
//
#include <hip/hip_runtime.h>
#include <hip/hip_bf16.h>
#include <stdint.h>

typedef _Float16 f16x8 __attribute__((ext_vector_type(8)));
typedef float f32x4 __attribute__((ext_vector_type(4)));

#define MFMA_F16(A, B, C) __builtin_amdgcn_mfma_f32_16x16x32_f16(A, B, C, 0, 0, 0)
#define GLOAD_LDS16(g, l)                                                     \
    __builtin_amdgcn_global_load_lds(                                         \
        (const __attribute__((address_space(1))) void*)(g),                   \
        (__attribute__((address_space(3))) void*)(l), 16, 0, 0)

constexpr int Bb = 4, Nn = 4096, Cc = 256;
constexpr int BQ = 128;          // q rows per block (8 waves x 16)
constexpr int BK = 64;           // k/v rows per tile
constexpr int NT = Nn / BK;
constexpr int KPAD = 256;        // 512B row stride; swizzle via pre-swizzled source
constexpr int VPAD = 64;         // 128B row stride; swizzle via pre-swizzled source
constexpr int PPAD = 72;         // R2-exact (144B stride, unswizzled)
// LDS: 2*sK 65536 + 2*sVt 65536 + sP 18432 = 149504 B

constexpr size_t ASZ = (size_t)2 * Bb * Nn * Cc;     // elems per ws array
constexpr size_t WS_NEED = ASZ * 2 * 3;              // bytes: hi + lo + vt

// ---------------- prep: fp32 -> fp16 hi/lo + transposed hi ----------------
__global__ __launch_bounds__(256)
void prep_kernel(const float* __restrict__ xa, const float* __restrict__ xb,
                 _Float16* __restrict__ hi, _Float16* __restrict__ lo,
                 _Float16* __restrict__ vt)
{
    const int n0 = blockIdx.x * 64, c0 = blockIdx.y * 64, ib = blockIdx.z;
    const float* x = ((ib >> 2) == 0 ? xa : xb) + (size_t)(ib & 3) * Nn * Cc;
    const size_t base = (size_t)ib * Nn * Cc;
    __shared__ ushort tile[64][68];
    const int t = threadIdx.x;
    const int r0 = t >> 4;            // 0..15
    const int c4 = (t & 15) * 4;      // 0,4,..,60
    #pragma unroll
    for (int ii = 0; ii < 4; ++ii) {
        const int r = r0 + ii * 16;
        float4 v = *(const float4*)&x[(size_t)(n0 + r) * Cc + c0 + c4];
        float vv[4] = {v.x, v.y, v.z, v.w};
        union { _Float16 h[4]; uint2 q; } H, L;
        #pragma unroll
        for (int e = 0; e < 4; ++e) {
            _Float16 h = (_Float16)vv[e];
            H.h[e] = h;
            L.h[e] = (_Float16)(vv[e] - (float)h);
        }
        *(uint2*)&hi[base + (size_t)(n0 + r) * Cc + c0 + c4] = H.q;
        *(uint2*)&lo[base + (size_t)(n0 + r) * Cc + c0 + c4] = L.q;
        *(uint2*)&tile[r][c4] = H.q;
    }
    __syncthreads();
    const int j4 = (t & 15) * 4;
    #pragma unroll
    for (int ii = 0; ii < 4; ++ii) {
        const int cr = r0 + ii * 16;
        ushort4 o;
        o.x = tile[j4 + 0][cr]; o.y = tile[j4 + 1][cr];
        o.z = tile[j4 + 2][cr]; o.w = tile[j4 + 3][cr];
        *(ushort4*)&vt[base + (size_t)(c0 + cr) * Nn + n0 + j4] = o;
    }
}

// ---------------- main attention ----------------
template<bool PREP>
__global__ __launch_bounds__(512, 1)
void attn_kernel(const float* __restrict__ xa, const float* __restrict__ xb,
                 const float* __restrict__ gamma_p, float* __restrict__ out,
                 const _Float16* __restrict__ hi, const _Float16* __restrict__ lo,
                 const _Float16* __restrict__ vt)
{
    const int qtile = blockIdx.x, b = blockIdx.y, dir = blockIdx.z;
    const float* qsrc = (dir == 0 ? xa : xb) + (size_t)b * Nn * Cc;
    const float* ksrc = (dir == 0 ? xb : xa) + (size_t)b * Nn * Cc;
    float* outp = out + (size_t)dir * Bb * Nn * Cc + (size_t)b * Nn * Cc;
    const int qib = dir * Bb + b;
    const int kib = (dir ^ 1) * Bb + b;
    const _Float16* qhiB = hi + (size_t)qib * Nn * Cc;
    const _Float16* qloB = lo + (size_t)qib * Nn * Cc;
    const _Float16* kB   = hi + (size_t)kib * Nn * Cc;
    const _Float16* vtB  = vt + (size_t)qib * Nn * Cc;   // V^T of q-source

    __shared__ _Float16 sK[2][BK][KPAD];    // K (fp16 hi); swizzled via source
    __shared__ _Float16 sVt[2][Cc][VPAD];   // sVt[c][m] = V[m][c]; swizzled via source
    __shared__ _Float16 sP[8][16][PPAD];    // per-wave P tile [qrow][m] (R2-exact)

    const int t = threadIdx.x, lane = t & 63, w = t >> 6;
    const int l15 = lane & 15, g = lane >> 4;
    const int khalf = g * 8;
    const int rsw = (l15 & 7) << 3;         // read swizzle (row = *16 + l15)

    // ---- Q fragments, negated (MFMA yields logits = -E), fp16 hi/lo ----
    f16x8 qhi[8], qlo[8];
    const int qrow = qtile * BQ + w * 16 + l15;
    if constexpr (PREP) {
        #pragma unroll
        for (int j = 0; j < 8; ++j) {
            union { uint4 u; f16x8 h; } A, C2;
            A.u  = *(const uint4*)(qhiB + (size_t)qrow * Cc + j * 32 + khalf);
            C2.u = *(const uint4*)(qloB + (size_t)qrow * Cc + j * 32 + khalf);
            A.u.x ^= 0x80008000u; A.u.y ^= 0x80008000u; A.u.z ^= 0x80008000u; A.u.w ^= 0x80008000u;
            C2.u.x ^= 0x80008000u; C2.u.y ^= 0x80008000u; C2.u.z ^= 0x80008000u; C2.u.w ^= 0x80008000u;
            qhi[j] = A.h; qlo[j] = C2.h;
        }
    } else {
        const float* qb = qsrc + (size_t)qrow * Cc;
        #pragma unroll
        for (int j = 0; j < 8; ++j) {
            float4 v0 = *(const float4*)(qb + j * 32 + khalf);
            float4 v1 = *(const float4*)(qb + j * 32 + khalf + 4);
            float xv[8] = {v0.x, v0.y, v0.z, v0.w, v1.x, v1.y, v1.z, v1.w};
            #pragma unroll
            for (int e = 0; e < 8; ++e) {
                float xn = -xv[e];
                _Float16 h = (_Float16)xn;
                qhi[j][e] = h;
                qlo[j][e] = (_Float16)(xn - (float)h);
            }
        }
    }

    f32x4 O[16];
    #pragma unroll
    for (int i = 0; i < 16; ++i) O[i] = (f32x4){0.f, 0.f, 0.f, 0.f};
    float mrow[4] = {-INFINITY, -INFINITY, -INFINITY, -INFINITY};
    float lsum[4] = {0.f, 0.f, 0.f, 0.f};

    // ---- global_load_lds staging maps: linear LDS dest, pre-swizzled source ----
    // sK: wave w covers rows w*8..w*8+7 via 4 x 1KB insts (2 rows each).
    const int krow0 = w * 8;
    const int klsub = lane >> 5;            // row within inst (0..1)
    int offK[4];
    #pragma unroll
    for (int i = 0; i < 4; ++i) {
        const int rsub = i * 2 + klsub;                     // row mod 8 (krow0 % 8 == 0)
        const int sc = ((lane & 31) * 8) ^ ((rsub & 7) << 3);
        offK[i] = (krow0 + rsub) * Cc + sc;
    }
    // sVt: wave w covers rows w*32..w*32+31 via 4 x 1KB insts (8 rows each).
    const int vrow0 = w * 32;
    const int vlsub = lane >> 3;            // row within inst (0..7) == row mod 8
    const int vcol  = ((lane & 7) * 8) ^ ((vlsub & 7) << 3);
    int offV[4];
    #pragma unroll
    for (int i = 0; i < 4; ++i)
        offV[i] = (vrow0 + i * 8 + vlsub) * Nn + vcol;

    auto stage = [&](int bufi, int m0) {
        #pragma unroll
        for (int i = 0; i < 4; ++i)
            GLOAD_LDS16(kB + (size_t)m0 * Cc + offK[i], &sK[bufi][krow0 + i * 2][0]);
        #pragma unroll
        for (int i = 0; i < 4; ++i)
            GLOAD_LDS16(vtB + (size_t)m0 + offV[i], &sVt[bufi][vrow0 + i * 8][0]);
    };

    auto compute = [&](int cur) {
        // ---- S = (-Q) K^T : q split fp16 hi/lo, k single fp16 ----
        f32x4 S[4];
        #pragma unroll
        for (int s = 0; s < 4; ++s) S[s] = (f32x4){0.f, 0.f, 0.f, 0.f};
        __builtin_amdgcn_s_setprio(1);
        #pragma unroll
        for (int j = 0; j < 8; ++j) {
            const int ko = j * 32 + khalf;
            f16x8 k0 = *(const f16x8*)&sK[cur][l15][ko ^ rsw];
            f16x8 k1 = *(const f16x8*)&sK[cur][16 + l15][ko ^ rsw];
            f16x8 k2 = *(const f16x8*)&sK[cur][32 + l15][ko ^ rsw];
            f16x8 k3 = *(const f16x8*)&sK[cur][48 + l15][ko ^ rsw];
            S[0] = MFMA_F16(qhi[j], k0, S[0]);
            S[1] = MFMA_F16(qhi[j], k1, S[1]);
            S[2] = MFMA_F16(qhi[j], k2, S[2]);
            S[3] = MFMA_F16(qhi[j], k3, S[3]);
            S[0] = MFMA_F16(qlo[j], k0, S[0]);
            S[1] = MFMA_F16(qlo[j], k1, S[1]);
            S[2] = MFMA_F16(qlo[j], k2, S[2]);
            S[3] = MFMA_F16(qlo[j], k3, S[3]);
        }
        __builtin_amdgcn_s_setprio(0);

        // ---- online softmax: per-tile max reduce; sum deferred to epilogue ----
        float tmax4[4];
        bool need = false;
        #pragma unroll
        for (int r = 0; r < 4; ++r) {
            float tm = fmaxf(fmaxf(S[0][r], S[1][r]), fmaxf(S[2][r], S[3][r]));
            #pragma unroll
            for (int off = 8; off >= 1; off >>= 1)
                tm = fmaxf(tm, __shfl_xor(tm, off, 64));
            tmax4[r] = tm;
            need = need || (tm > mrow[r] + 8.f);
        }
        if (__any(need)) {      // rescale path (rare after warmup: defer-max THR=8)
            float a4[4];
            #pragma unroll
            for (int r = 0; r < 4; ++r) {
                float mn = fmaxf(mrow[r], tmax4[r]);
                a4[r] = __expf(mrow[r] - mn);
                mrow[r] = mn;
                lsum[r] *= a4[r];
            }
            #pragma unroll
            for (int i = 0; i < 16; ++i) {
                #pragma unroll
                for (int r = 0; r < 4; ++r) O[i][r] *= a4[r];
            }
        }
        const int prow = g * 4;
        #pragma unroll
        for (int r = 0; r < 4; ++r) {
            float ps = 0.f;
            #pragma unroll
            for (int s = 0; s < 4; ++s) {
                float p = __expf(S[s][r] - mrow[r]);
                ps += p;
                sP[w][prow + r][s * 16 + l15] = (_Float16)p;
            }
            lsum[r] += ps;
        }
        // order the same-wave LDS RAW at compile time and run time (rule #18)
        asm volatile("s_waitcnt lgkmcnt(0)" ::: "memory");
        __builtin_amdgcn_sched_barrier(0);

        // ---- O += P @ V ----
        f16x8 pa0 = *(const f16x8*)&sP[w][l15][khalf];
        f16x8 pa1 = *(const f16x8*)&sP[w][l15][32 + khalf];
        __builtin_amdgcn_s_setprio(1);
        #pragma unroll
        for (int i = 0; i < 16; ++i) {
            f16x8 vb0 = *(const f16x8*)&sVt[cur][i * 16 + l15][khalf ^ rsw];
            f16x8 vb1 = *(const f16x8*)&sVt[cur][i * 16 + l15][(32 + khalf) ^ rsw];
            O[i] = MFMA_F16(pa0, vb0, O[i]);
            O[i] = MFMA_F16(pa1, vb1, O[i]);
        }
        __builtin_amdgcn_s_setprio(0);
    };

    if constexpr (PREP) {
        stage(0, 0);
        __syncthreads();                    // implicit vmcnt(0): tile 0 landed
        for (int ti = 0; ti < NT; ++ti) {
            if (ti + 1 < NT) stage((ti & 1) ^ 1, (ti + 1) * BK);  // async, lands during compute
            compute(ti & 1);
            __syncthreads();                // reads of buf cur done; prefetch drained
        }
    } else {
        const int fr = t & 63, fc = (t >> 6) * 32;
        const int fsw = (fr & 7) << 3;
        for (int ti = 0; ti < NT; ++ti) {
            const int m0 = ti * BK;
            __syncthreads();
            #pragma unroll
            for (int e = 0; e < 32; e += 4) {
                float4 kv = *(const float4*)&ksrc[(size_t)(m0 + fr) * Cc + fc + e];
                sK[0][fr][(fc + e + 0) ^ fsw] = (_Float16)kv.x;
                sK[0][fr][(fc + e + 1) ^ fsw] = (_Float16)kv.y;
                sK[0][fr][(fc + e + 2) ^ fsw] = (_Float16)kv.z;
                sK[0][fr][(fc + e + 3) ^ fsw] = (_Float16)kv.w;
                float4 xv = *(const float4*)&qsrc[(size_t)(m0 + fr) * Cc + fc + e];
                sVt[0][fc + e + 0][fr ^ (((fc + e + 0) & 7) << 3)] = (_Float16)xv.x;
                sVt[0][fc + e + 1][fr ^ (((fc + e + 1) & 7) << 3)] = (_Float16)xv.y;
                sVt[0][fc + e + 2][fr ^ (((fc + e + 2) & 7) << 3)] = (_Float16)xv.z;
                sVt[0][fc + e + 3][fr ^ (((fc + e + 3) & 7) << 3)] = (_Float16)xv.w;
            }
            __syncthreads();
            compute(0);
        }
    }

    // ---- epilogue: final sum-reduce, normalize, gamma*out + residual ----
    const float gma = gamma_p[0];
    #pragma unroll
    for (int r = 0; r < 4; ++r) {
        float lv = lsum[r];
        #pragma unroll
        for (int off = 8; off >= 1; off >>= 1)
            lv += __shfl_xor(lv, off, 64);
        const float inv = 1.f / lv;
        const int row = qtile * BQ + w * 16 + g * 4 + r;
        const size_t ro = (size_t)row * Cc + l15;
        #pragma unroll
        for (int i = 0; i < 16; ++i) {
            float o = O[i][r] * inv;
            outp[ro + i * 16] = gma * o + qsrc[ro + i * 16];
        }
    }
}

extern "C" void kernel_launch(void* const* d_in, const int* in_sizes, int n_in,
                              void* d_out, int out_size, void* d_ws, size_t ws_size,
                              hipStream_t stream) {
    (void)in_sizes; (void)n_in; (void)out_size;
    const float* xa = (const float*)d_in[0];
    const float* xb = (const float*)d_in[1];
    const float* gm = (const float*)d_in[2];
    float* out = (float*)d_out;

    dim3 agrid(Nn / BQ, Bb, 2);
    if (ws_size >= WS_NEED) {
        _Float16* hi = (_Float16*)d_ws;
        _Float16* lo = hi + ASZ;
        _Float16* vt = lo + ASZ;
        prep_kernel<<<dim3(Nn / 64, Cc / 64, 2 * Bb), 256, 0, stream>>>(xa, xb, hi, lo, vt);
        attn_kernel<true><<<agrid, 512, 0, stream>>>(xa, xb, gm, out, hi, lo, vt);
    } else {
        attn_kernel<false><<<agrid, 512, 0, stream>>>(xa, xb, gm, out, nullptr, nullptr, nullptr);
    }
}